// Round 2
// baseline (308.804 us; speedup 1.0000x reference)
//
#include <hip/hip_runtime.h>
#include <math.h>

#define TPB 256
#define W 64
#define H 64
#define LDSW 68   // r5 row stride in floats; breaks pow-2 bank stride, keeps 16B alignment

typedef float f32x4 __attribute__((ext_vector_type(4)));

__device__ __forceinline__ f32x4 max4(f32x4 a, f32x4 b) {
    f32x4 r;
    r.x = fmaxf(a.x, b.x); r.y = fmaxf(a.y, b.y);
    r.z = fmaxf(a.z, b.z); r.w = fmaxf(a.w, b.w);
    return r;
}

// LDS-only barrier: orders ds_write -> ds_read across the workgroup WITHOUT
// draining vmcnt. __syncthreads() emits s_waitcnt vmcnt(0) lgkmcnt(0) before
// s_barrier, which parks every wave until all nontemporal HBM stores (and any
// in-flight prefetch loads) complete -- pure stall, since global outputs are
// per-thread disjoint and never re-read. Single asm block so the scheduler
// cannot slide a ds_read between the waitcnt and the barrier.
__device__ __forceinline__ void lds_barrier() {
    asm volatile("s_waitcnt lgkmcnt(0)\n\ts_barrier" ::: "memory");
}

// ---- P1: pool0 nt-store + in-register row-max-5 (halo via wave shuffle) -> LDS ----
__device__ __forceinline__ void p1_rest(const f32x4 v[4], float* __restrict__ s,
                                        float* __restrict__ outimg, int tid) {
    const int  lane = tid & 63;
    const int  lm1 = (lane - 1) & 63;
    const int  lp1 = (lane + 1) & 63;
    const bool qlo = (lane & 15) == 0;    // strip starts at x=0  -> left halo = -inf
    const bool qhi = (lane & 15) == 15;   // strip ends at x=63   -> right halo = -inf
    const float NEG = -INFINITY;
    f32x4* o4 = (f32x4*)outimg;
    #pragma unroll
    for (int i = 0; i < 4; ++i) {
        const int idx = tid + TPB * i;    // float4 index 0..1023
        f32x4 t = v[i];
        __builtin_nontemporal_store(t, o4 + idx);    // pool 0 = x
        float e0 = __shfl(t.z, lm1, 64);
        float e1 = __shfl(t.w, lm1, 64);
        float e6 = __shfl(t.x, lp1, 64);
        float e7 = __shfl(t.y, lp1, 64);
        if (qlo) { e0 = NEG; e1 = NEG; }
        if (qhi) { e6 = NEG; e7 = NEG; }
        const float e2 = t.x, e3 = t.y, e4 = t.z, e5 = t.w;
        const float p0 = fmaxf(e0, e1), p1 = fmaxf(e1, e2), p2 = fmaxf(e2, e3);
        const float p3 = fmaxf(e3, e4), p4 = fmaxf(e4, e5), p5 = fmaxf(e5, e6);
        f32x4 r;                           // r5 at x0..x0+3
        r.x = fmaxf(fmaxf(p0, p2), e4);
        r.y = fmaxf(fmaxf(p1, p3), e5);
        r.z = fmaxf(fmaxf(p2, p4), e6);
        r.w = fmaxf(fmaxf(p3, p5), e7);
        const int y = idx >> 4;
        const int q = idx & 15;
        *(f32x4*)&s[y * LDSW + 4 * q] = r;
    }
}

// ---- P2: column pass on r5, thread owns a 4-wide x 4-tall tile.
//      ds_read_b128 in, float4 vertical max tree, lane+-1 shuffles for the
//      horizontal 9/13 widening, global_store_dwordx4 out for ALL pools. ----
__device__ __forceinline__ void p2(const float* __restrict__ s,
                                   float* __restrict__ outimg, int tid) {
    const float NEG = -INFINITY;
    const size_t pstr = (size_t)256 * H * W;
    const int g    = tid & 15;            // col group: x = 4g..4g+3
    const int x0   = g << 2;
    const int y0   = (tid >> 4) << 2;     // row group: y = y0..y0+3
    const int lane = tid & 63;
    const int lm1  = (lane - 1) & 63;     // left neighbor col-group (same rows)
    const int lp1  = (lane + 1) & 63;     // right neighbor col-group
    const bool qlo = (g == 0);
    const bool qhi = (g == 15);

    f32x4 cv[16];                          // r5[y0-6 .. y0+9][x0..x0+3], -inf out of range
    #pragma unroll
    for (int j = 0; j < 16; ++j) {
        const int y  = y0 - 6 + j;
        const int yc = y < 0 ? 0 : (y > 63 ? 63 : y);
        f32x4 v = *(const f32x4*)&s[yc * LDSW + x0];
        if (y < 0 || y > 63) v = (f32x4){NEG, NEG, NEG, NEG};
        cv[j] = v;
    }
    // shared pairwise-max tree (vertical)
    f32x4 m2[15], m4[13], m8[9];
    #pragma unroll
    for (int j = 0; j < 15; ++j) m2[j] = max4(cv[j], cv[j + 1]);
    #pragma unroll
    for (int j = 0; j < 13; ++j) m4[j] = max4(m2[j], m2[j + 2]);
    #pragma unroll
    for (int j = 0; j < 9;  ++j) m8[j] = max4(m4[j], m4[j + 4]);

    float* o5  = outimg +     pstr;
    float* o9  = outimg + 2 * pstr;
    float* o13 = outimg + 3 * pstr;
    #pragma unroll
    for (int i = 0; i < 4; ++i) {
        // column maxes (windows 5/9/13 rows) at output row y0+i, cols x0..x0+3
        const f32x4 c5  = max4(m4[i + 4], cv[i + 8]);
        const f32x4 c9  = max4(m8[i + 2], cv[i + 10]);
        const f32x4 c13 = max4(max4(m8[i], m4[i + 8]), cv[i + 12]);

        __builtin_nontemporal_store(c5, (f32x4*)(o5 + (y0 + i) * W + x0));

        // pool9: out[x] = max(c9[clamp(x-2)], c9[clamp(x+2)])
        const float Lz = __shfl(c9.z, lm1, 64);
        const float Lw = __shfl(c9.w, lm1, 64);
        const float Rx = __shfl(c9.x, lp1, 64);
        const float Ry = __shfl(c9.y, lp1, 64);
        const f32x4 lh9 = qlo ? (f32x4){c9.x, c9.x, c9.x, c9.y}
                              : (f32x4){Lz, Lw, c9.x, c9.y};
        const f32x4 rh9 = qhi ? (f32x4){c9.z, c9.w, c9.w, c9.w}
                              : (f32x4){c9.z, c9.w, Rx, Ry};
        __builtin_nontemporal_store(max4(lh9, rh9), (f32x4*)(o9 + (y0 + i) * W + x0));

        // pool13: out[x] = max(c13[clamp(x-4)], c13[x], c13[clamp(x+4)])
        f32x4 L13, R13;
        L13.x = __shfl(c13.x, lm1, 64); L13.y = __shfl(c13.y, lm1, 64);
        L13.z = __shfl(c13.z, lm1, 64); L13.w = __shfl(c13.w, lm1, 64);
        R13.x = __shfl(c13.x, lp1, 64); R13.y = __shfl(c13.y, lp1, 64);
        R13.z = __shfl(c13.z, lp1, 64); R13.w = __shfl(c13.w, lp1, 64);
        const f32x4 lh13 = qlo ? (f32x4){c13.x, c13.x, c13.x, c13.x} : L13;
        const f32x4 rh13 = qhi ? (f32x4){c13.w, c13.w, c13.w, c13.w} : R13;
        __builtin_nontemporal_store(max4(max4(lh13, c13), rh13),
                                    (f32x4*)(o13 + (y0 + i) * W + x0));
    }
}

__global__ __launch_bounds__(TPB, 2) void spp_kernel(const float* __restrict__ in,
                                                     float* __restrict__ out) {
    __shared__ __align__(16) float s_a[H * LDSW];   // 17,408 B
    __shared__ __align__(16) float s_b[H * LDSW];   // 17,408 B

    const int tid  = threadIdx.x;
    const int imgA = blockIdx.x * 2;
    const int imgB = imgA + 1;
    const size_t obaseA = (((size_t)(imgA >> 8)) * 1024 + (imgA & 255)) * (H * W);
    const size_t obaseB = (((size_t)(imgB >> 8)) * 1024 + (imgB & 255)) * (H * W);

    // ---- stage 1: issue A AND B loads up front (barriers no longer drain vmcnt,
    //      so B's ~900-cycle HBM latency hides under P1(A)+P2(A)), then P1(A) ----
    f32x4 va[4], vb[4];
    {
        const f32x4* inA = (const f32x4*)(in + (size_t)imgA * (H * W));
        const f32x4* inB = (const f32x4*)(in + (size_t)imgB * (H * W));
        #pragma unroll
        for (int i = 0; i < 4; ++i) va[i] = __builtin_nontemporal_load(inA + tid + TPB * i);
        #pragma unroll
        for (int i = 0; i < 4; ++i) vb[i] = __builtin_nontemporal_load(inB + tid + TPB * i);
    }
    p1_rest(va, s_a, out + obaseA, tid);
    lds_barrier();                         // LDS-only: nt stores + B loads stay in flight

    // ---- stage 2: P2(A) store burst, then finish P1(B) (vb long since landed) ----
    p2(s_a, out + obaseA, tid);
    p1_rest(vb, s_b, out + obaseB, tid);
    lds_barrier();                         // LDS-only: P2(A)'s 12 stores stay in flight

    // ---- stage 3: P2(B) ----
    p2(s_b, out + obaseB, tid);
}

extern "C" void kernel_launch(void* const* d_in, const int* in_sizes, int n_in,
                              void* d_out, int out_size, void* d_ws, size_t ws_size,
                              hipStream_t stream) {
    const float* x = (const float*)d_in[0];
    float* out = (float*)d_out;
    // 4096 images, 2 per block (software-pipelined), all-dwordx4 output path
    spp_kernel<<<dim3(2048), dim3(TPB), 0, stream>>>(x, out);
}